// Round 4
// baseline (461.879 us; speedup 1.0000x reference)
//
#include <hip/hip_runtime.h>
#include <math.h>

// ---- static config ----
// NS=16, NV=4, C=32, RDIM=32, FC_DIM=64, WNUM=416, L=2
#define SQRT3f     1.7320508075688772f
#define INV_SQRT3f 0.5773502691896258f
#define INV_SQRT2f 0.7071067811865476f
#define A0f        0.22360679774997896f   // 1/sqrt(16+4)
#define A1f        0.20412414523193150f   // 1/sqrt(16+8)

typedef __attribute__((ext_vector_type(8))) short bf16x8;
typedef __attribute__((ext_vector_type(4))) float f32x4;

__device__ __forceinline__ float4 ld4(const float* p) {
    return *reinterpret_cast<const float4*>(p);
}

__device__ __forceinline__ unsigned short f2bf(float x) {
    unsigned int u = __float_as_uint(x);
    u = (u + 0x7FFFu + ((u >> 16) & 1u)) >> 16;   // RNE
    return (unsigned short)u;
}
__device__ __forceinline__ float bf2f(unsigned short u) {
    return __uint_as_float(((unsigned int)u) << 16);
}

// out[16] = in[16] @ W[16,16] + b ; optional relu
template<bool RELU>
__device__ __forceinline__ void mm16x16(const float* in, const float* __restrict__ W,
                                        const float* __restrict__ b, float* out)
{
#pragma unroll
    for (int t = 0; t < 16; ++t) out[t] = b[t];
#pragma unroll
    for (int s = 0; s < 16; ++s) {
        float a = in[s];
#pragma unroll
        for (int q = 0; q < 4; ++q) {
            float4 w = ld4(W + s * 16 + q * 4);
            out[q*4+0] += a * w.x; out[q*4+1] += a * w.y;
            out[q*4+2] += a * w.z; out[q*4+3] += a * w.w;
        }
    }
    if (RELU) {
#pragma unroll
        for (int t = 0; t < 16; ++t) out[t] = fmaxf(out[t], 0.f);
    }
}

// h0[n] = MLP(node_feats[n] @ enc_W + enc_b)
__global__ __launch_bounds__(256)
void node_embed_kernel(const float* __restrict__ nf,
                       const float* __restrict__ encW, const float* __restrict__ encb,
                       const float* __restrict__ neW1, const float* __restrict__ neb1,
                       const float* __restrict__ neW2, const float* __restrict__ neb2,
                       float* __restrict__ h0, int N)
{
    int n = blockIdx.x * blockDim.x + threadIdx.x;
    if (n >= N) return;
    float x[16];
#pragma unroll
    for (int s = 0; s < 16; ++s) x[s] = encb[s];
    for (int i = 0; i < 64; ++i) {
        float a = nf[n * 64 + i];
#pragma unroll
        for (int q = 0; q < 4; ++q) {
            float4 w = ld4(encW + i * 16 + q * 4);
            x[q*4+0] += a * w.x; x[q*4+1] += a * w.y;
            x[q*4+2] += a * w.z; x[q*4+3] += a * w.w;
        }
    }
    float h[16], o[16];
    mm16x16<true >(x, neW1, neb1, h);
    mm16x16<false>(h, neW2, neb2, o);
#pragma unroll
    for (int j = 0; j < 16; ++j) h0[n * 16 + j] = o[j];
}

// ---- counting sort of edges by src ----
__global__ __launch_bounds__(256)
void hist_kernel(const int* __restrict__ srcI, int* __restrict__ cntI, int E)
{
    int e = blockIdx.x * blockDim.x + threadIdx.x;
    if (e < E) atomicAdd(&cntI[srcI[e]], 1);
}

__global__ __launch_bounds__(1024)
void scan_kernel(const int* __restrict__ cntI, int* __restrict__ start,
                 int* __restrict__ cursor, float* __restrict__ invcnt, int N)
{
    __shared__ int sd[1024];
    int tid = threadIdx.x;
    int run = 0;
    for (int c0 = 0; c0 < N; c0 += 1024) {
        int i = c0 + tid;
        int v = (i < N) ? cntI[i] : 0;
        sd[tid] = v;
        __syncthreads();
        for (int s = 1; s < 1024; s <<= 1) {
            int t = (tid >= s) ? sd[tid - s] : 0;
            __syncthreads();
            sd[tid] += t;
            __syncthreads();
        }
        int incl = sd[tid];
        int total = sd[1023];
        if (i < N) {
            int st = run + incl - v;
            start[i] = st;
            cursor[i] = st;
            invcnt[i] = 1.0f / fmaxf((float)v, 1.0f);
        }
        run += total;
        __syncthreads();
    }
}

__global__ __launch_bounds__(256)
void perm_kernel(const int* __restrict__ srcI, int* __restrict__ cursor,
                 int* __restrict__ perm, int E)
{
    int e = blockIdx.x * blockDim.x + threadIdx.x;
    if (e >= E) return;
    int p = atomicAdd(&cursor[srcI[e]], 1);
    perm[p] = e;
}

// per-sorted-edge: y1, edge_attr = MLP(edge_attr_in) + MLP(rbf(d)); writes in
// sorted order p, plus srcS/dstS.
__global__ __launch_bounds__(256)
void edge_pre_kernel(const float* __restrict__ pos, const float* __restrict__ eain,
                     const int* __restrict__ srcI, const int* __restrict__ dstI,
                     const int* __restrict__ perm,
                     const float* __restrict__ eeW1, const float* __restrict__ eeb1,
                     const float* __restrict__ eeW2, const float* __restrict__ eeb2,
                     const float* __restrict__ reW1, const float* __restrict__ reb1,
                     const float* __restrict__ reW2, const float* __restrict__ reb2,
                     float* __restrict__ eattr, float* __restrict__ y1s,
                     int* __restrict__ srcS, int* __restrict__ dstS, int E)
{
    int p = blockIdx.x * blockDim.x + threadIdx.x;
    if (p >= E) return;
    int e = perm[p];
    int s = srcI[e], d = dstI[e];
    srcS[p] = s; dstS[p] = d;
    float vx = pos[s*3+0] - pos[d*3+0];
    float vy = pos[s*3+1] - pos[d*3+1];
    float vz = pos[s*3+2] - pos[d*3+2];
    float dist = sqrtf(vx*vx + vy*vy + vz*vz);
    float inv = 1.f / fmaxf(dist, 1e-9f);
    y1s[p*3+0] = SQRT3f * vx * inv;
    y1s[p*3+1] = SQRT3f * vy * inv;
    y1s[p*3+2] = SQRT3f * vz * inv;

    const float step  = 12.0f / 31.0f;
    const float coeff = -0.5f / (step * step);
    float rbf[32];
#pragma unroll
    for (int j = 0; j < 32; ++j) {
        float t = dist - (float)j * step;
        rbf[j] = expf(coeff * t * t);
    }

    float ein[16];
#pragma unroll
    for (int j = 0; j < 16; ++j) ein[j] = eain[(size_t)e * 16 + j];

    float t1[16], a1v[16];
    mm16x16<true >(ein, eeW1, eeb1, t1);
    mm16x16<false>(t1, eeW2, eeb2, a1v);

    float t2[16];
#pragma unroll
    for (int t = 0; t < 16; ++t) t2[t] = reb1[t];
    for (int j = 0; j < 32; ++j) {
        float a = rbf[j];
#pragma unroll
        for (int q = 0; q < 4; ++q) {
            float4 w = ld4(reW1 + j * 16 + q * 4);
            t2[q*4+0] += a * w.x; t2[q*4+1] += a * w.y;
            t2[q*4+2] += a * w.z; t2[q*4+3] += a * w.w;
        }
    }
#pragma unroll
    for (int t = 0; t < 16; ++t) t2[t] = fmaxf(t2[t], 0.f);
    float a2v[16];
    mm16x16<false>(t2, reW2, reb2, a2v);

#pragma unroll
    for (int j = 0; j < 16; ++j) eattr[(size_t)p * 16 + j] = a1v[j] + a2v[j];
}

// pack fc2W (both layers) into MFMA B-fragment order, bf16:
// w2p[layer][nt][ks][lane][j] = W2[ks*32 + (lane>>4)*8 + j][nt*16 + (lane&15)]
__global__ void pack_w2_kernel(const float* __restrict__ fc2W, unsigned short* __restrict__ w2p)
{
    int idx = blockIdx.x * blockDim.x + threadIdx.x;
    if (idx >= 2 * 26 * 2 * 64) return;
    int lane  = idx & 63;
    int ks    = (idx >> 6) & 1;
    int nt    = (idx >> 7) % 26;
    int layer = idx / (26 * 2 * 64);
    const float* W = fc2W + (size_t)layer * 64 * 416;
    unsigned short* out = w2p + (size_t)layer * 26 * 2 * 64 * 8
                              + (size_t)((nt * 2 + ks) * 64 + lane) * 8;
    int k0 = ks * 32 + (lane >> 4) * 8;
    int c  = nt * 16 + (lane & 15);
#pragma unroll
    for (int j = 0; j < 8; ++j) out[j] = f2bf(W[(size_t)(k0 + j) * 416 + c]);
}

// ======= fused per-layer kernel =======
// Phase 1 (thread = sorted edge): hid = relu([eattr|h0[src]|h0[dst]] @ W1 + b1)
//   -> bf16 -> LDS (XOR-swizzled 16B chunks); x0/x1/dot/cr/y1 -> LDS bf16.
// Phase 2 (4 waves x 64 edges): MFMA over 26 N-tiles of W2, TP epilogue,
//   coalesced per-edge writes of o0 (16) / o1 (12) — no atomics.
template<bool HAS_L1>
__global__ __launch_bounds__(256, 2)
void fused_tp_kernel(const float* __restrict__ h0, const float* __restrict__ h1,
                     const float* __restrict__ eattr, const float* __restrict__ y1s,
                     const int* __restrict__ srcS, const int* __restrict__ dstS,
                     const float* __restrict__ fc1W, const float* __restrict__ fc1b,
                     const unsigned short* __restrict__ w2p,
                     const float* __restrict__ b2,
                     float* __restrict__ oo0, float* __restrict__ oo1, int E)
{
    __shared__ unsigned short hids[256 * 64];   // swizzled: chunk' = chunk ^ (row&7)
    __shared__ unsigned short x0s[256 * 18];    // pad to 18 (stride 36B)
    __shared__ unsigned short x1s[256 * 14];
    __shared__ unsigned short dots[256 * 6];
    __shared__ unsigned short crs[256 * 14];
    __shared__ unsigned short y1l[256 * 6];
    __shared__ float w1s[48 * 64];
    __shared__ float b1s[64];

    int tid = threadIdx.x;
    for (int i = tid; i < 48 * 64; i += 256) w1s[i] = fc1W[i];
    if (tid < 64) b1s[tid] = fc1b[tid];
    __syncthreads();

    int ebase = blockIdx.x * 256;
    {
        int p = ebase + tid;
        int s = srcS[p], d = dstS[p];

        float ea[48];
#pragma unroll
        for (int q = 0; q < 4; ++q) {
            float4 v = ld4(eattr + (size_t)p * 16 + q * 4);
            ea[q*4+0] = v.x; ea[q*4+1] = v.y; ea[q*4+2] = v.z; ea[q*4+3] = v.w;
        }
#pragma unroll
        for (int q = 0; q < 4; ++q) {
            float4 v = ld4(h0 + (size_t)s * 16 + q * 4);
            ea[16+q*4+0] = v.x; ea[16+q*4+1] = v.y; ea[16+q*4+2] = v.z; ea[16+q*4+3] = v.w;
        }
#pragma unroll
        for (int q = 0; q < 4; ++q) {
            float4 v = ld4(h0 + (size_t)d * 16 + q * 4);
            ea[32+q*4+0] = v.x; ea[32+q*4+1] = v.y; ea[32+q*4+2] = v.z; ea[32+q*4+3] = v.w;
        }
#pragma unroll
        for (int j = 0; j < 16; ++j) x0s[tid * 18 + j] = f2bf(ea[32 + j]);

        float yv0 = y1s[(size_t)p*3+0], yv1 = y1s[(size_t)p*3+1], yv2 = y1s[(size_t)p*3+2];
        y1l[tid*6+0] = f2bf(yv0); y1l[tid*6+1] = f2bf(yv1); y1l[tid*6+2] = f2bf(yv2);

        if (HAS_L1) {
#pragma unroll
            for (int v = 0; v < 4; ++v) {
                float xa = h1[(size_t)d*12 + v*3 + 0];
                float xb = h1[(size_t)d*12 + v*3 + 1];
                float xc = h1[(size_t)d*12 + v*3 + 2];
                x1s[tid*14 + v*3 + 0] = f2bf(xa);
                x1s[tid*14 + v*3 + 1] = f2bf(xb);
                x1s[tid*14 + v*3 + 2] = f2bf(xc);
                dots[tid*6 + v] = f2bf((xa*yv0 + xb*yv1 + xc*yv2) * INV_SQRT3f);
                crs[tid*14 + v*3 + 0] = f2bf((xb*yv2 - xc*yv1) * INV_SQRT2f);
                crs[tid*14 + v*3 + 1] = f2bf((xc*yv0 - xa*yv2) * INV_SQRT2f);
                crs[tid*14 + v*3 + 2] = f2bf((xa*yv1 - xb*yv0) * INV_SQRT2f);
            }
        }

        float hid[64];
#pragma unroll
        for (int k = 0; k < 64; ++k) hid[k] = b1s[k];
        for (int j = 0; j < 48; ++j) {
            float a = ea[j];
#pragma unroll
            for (int q = 0; q < 16; ++q) {
                float4 w = *reinterpret_cast<const float4*>(&w1s[j * 64 + q * 4]);
                hid[q*4+0] += a * w.x; hid[q*4+1] += a * w.y;
                hid[q*4+2] += a * w.z; hid[q*4+3] += a * w.w;
            }
        }
#pragma unroll
        for (int g = 0; g < 8; ++g) {
            uint4 pk;
            unsigned int c0 = f2bf(fmaxf(hid[g*8+0], 0.f)), c1 = f2bf(fmaxf(hid[g*8+1], 0.f));
            unsigned int c2 = f2bf(fmaxf(hid[g*8+2], 0.f)), c3 = f2bf(fmaxf(hid[g*8+3], 0.f));
            unsigned int c4 = f2bf(fmaxf(hid[g*8+4], 0.f)), c5 = f2bf(fmaxf(hid[g*8+5], 0.f));
            unsigned int c6 = f2bf(fmaxf(hid[g*8+6], 0.f)), c7 = f2bf(fmaxf(hid[g*8+7], 0.f));
            pk.x = c0 | (c1 << 16); pk.y = c2 | (c3 << 16);
            pk.z = c4 | (c5 << 16); pk.w = c6 | (c7 << 16);
            int chunk = g ^ (tid & 7);
            *reinterpret_cast<uint4*>(&hids[tid * 64 + chunk * 8]) = pk;
        }
    }
    __syncthreads();

    // ---- phase 2 ----
    int wave = tid >> 6;
    int lane = tid & 63;
    int col = lane & 15;
    int grp = lane >> 4;
    int mrow0 = wave * 64;     // this wave's 64 edges: local rows mrow0..mrow0+63

    bf16x8 a[4][2];
#pragma unroll
    for (int m = 0; m < 4; ++m) {
        int row = mrow0 + m * 16 + col;
        int c0 = grp ^ (col & 7);
        int c1 = (grp + 4) ^ (col & 7);
        a[m][0] = *reinterpret_cast<const bf16x8*>(&hids[row * 64 + c0 * 8]);
        a[m][1] = *reinterpret_cast<const bf16x8*>(&hids[row * 64 + c1 * 8]);
    }

    float o0a[4][4];
    float t011p[4][4];
    float o1p[4][4][3];
#pragma unroll
    for (int m = 0; m < 4; ++m)
#pragma unroll
        for (int r = 0; r < 4; ++r) {
            o0a[m][r] = 0.f; t011p[m][r] = 0.f;
            o1p[m][r][0] = 0.f; o1p[m][r][1] = 0.f; o1p[m][r][2] = 0.f;
        }

    const int NT = HAS_L1 ? 26 : 20;
    for (int nt = 0; nt < NT; ++nt) {
        const bf16x8* bp = reinterpret_cast<const bf16x8*>(
            w2p + (size_t)(nt * 2 * 64 + lane) * 8);
        bf16x8 b0 = bp[0];
        bf16x8 b1 = bp[64];
        float bias = b2[nt * 16 + col];
#pragma unroll
        for (int m = 0; m < 4; ++m) {
            f32x4 acc = {0.f, 0.f, 0.f, 0.f};
            acc = __builtin_amdgcn_mfma_f32_16x16x32_bf16(a[m][0], b0, acc, 0, 0, 0);
            acc = __builtin_amdgcn_mfma_f32_16x16x32_bf16(a[m][1], b1, acc, 0, 0, 0);
            int lx0 = mrow0 + m * 16 + grp * 4;
            if (nt < 16) {
#pragma unroll
                for (int r = 0; r < 4; ++r) {
                    float p = acc[r] + bias;
                    o0a[m][r] += bf2f(x0s[(lx0 + r) * 18 + nt]) * p;
                }
            } else if (nt < 20) {
                int n = (nt - 16) * 4 + (col >> 2);
#pragma unroll
                for (int r = 0; r < 4; ++r) {
                    float p = acc[r] + bias;
                    t011p[m][r] += bf2f(x0s[(lx0 + r) * 18 + n]) * p;
                }
            } else if (nt == 20) {
                int n = col >> 2;
#pragma unroll
                for (int r = 0; r < 4; ++r) {
                    float p = acc[r] + bias;
#pragma unroll
                    for (int d = 0; d < 3; ++d)
                        o1p[m][r][d] += bf2f(x1s[(lx0 + r) * 14 + n * 3 + d]) * p;
                }
            } else if (nt < 25) {
                int n = nt - 21;
#pragma unroll
                for (int r = 0; r < 4; ++r) {
                    float p = acc[r] + bias;
                    o0a[m][r] += bf2f(dots[(lx0 + r) * 6 + n]) * p;
                }
            } else {
                int n = col >> 2;
#pragma unroll
                for (int r = 0; r < 4; ++r) {
                    float p = acc[r] + bias;
#pragma unroll
                    for (int d = 0; d < 3; ++d)
                        o1p[m][r][d] += bf2f(crs[(lx0 + r) * 14 + n * 3 + d]) * p;
                }
            }
        }
    }

    // epilogue: reduce 4-lane partials (lanes col, col^4, col^8, col^12 share
    // o-class col&3 and the same edge), add t011*y1, coalesced store.
#pragma unroll
    for (int m = 0; m < 4; ++m) {
        int lx0 = mrow0 + m * 16 + grp * 4;
#pragma unroll
        for (int r = 0; r < 4; ++r) {
            int lx = lx0 + r;
            size_t e = (size_t)(ebase + lx);
            float t = t011p[m][r];
            t += __shfl_xor(t, 4);
            t += __shfl_xor(t, 8);
            float o1v[3];
#pragma unroll
            for (int d = 0; d < 3; ++d) {
                float v = o1p[m][r][d];
                v += __shfl_xor(v, 4);
                v += __shfl_xor(v, 8);
                o1v[d] = v + t * bf2f(y1l[lx * 6 + d]);
            }
            oo0[e * 16 + col] = A0f * o0a[m][r];
            if (col < 4) {
#pragma unroll
                for (int d = 0; d < 3; ++d)
                    oo1[e * 12 + col * 3 + d] = A1f * o1v[d];
            }
        }
    }
}

// residual update: h += (segment sum over sorted run) / max(cnt,1)
__global__ void node_update_kernel(float* __restrict__ h0, float* __restrict__ h1,
                                   const float* __restrict__ oo0, const float* __restrict__ oo1,
                                   const int* __restrict__ start, const int* __restrict__ cntI,
                                   const float* __restrict__ invcnt, int N)
{
    int j = threadIdx.x;                       // 0..31 (use 0..27)
    int n = blockIdx.x * blockDim.y + threadIdx.y;
    if (n >= N || j >= 28) return;
    int p0 = start[n], p1 = p0 + cntI[n];
    float acc = 0.f;
    if (j < 16) {
        for (int p = p0; p < p1; ++p) acc += oo0[(size_t)p * 16 + j];
        h0[(size_t)n * 16 + j] += acc * invcnt[n];
    } else {
        int m = j - 16;
        for (int p = p0; p < p1; ++p) acc += oo1[(size_t)p * 12 + m];
        h1[(size_t)n * 12 + m] += acc * invcnt[n];
    }
}

// final o3.Linear + sorter: out[n, c*4+0]=f0[n,c]; out[n, c*4+1+m]=f1[n,c,m]
__global__ __launch_bounds__(256)
void final_kernel(const float* __restrict__ h0, const float* __restrict__ h1,
                  const float* __restrict__ lin0, const float* __restrict__ lin1,
                  float* __restrict__ out, int N)
{
    int i = blockIdx.x * blockDim.x + threadIdx.x;
    if (i >= N * 32) return;
    int n = i >> 5, c = i & 31;
    float f0 = 0.f;
#pragma unroll
    for (int s = 0; s < 16; ++s) f0 += h0[n * 16 + s] * lin0[s * 32 + c];
    f0 *= 0.25f;                                // 1/sqrt(16)
    float f1x = 0.f, f1y = 0.f, f1z = 0.f;
#pragma unroll
    for (int v = 0; v < 4; ++v) {
        float w = lin1[v * 32 + c];
        f1x += h1[n * 12 + v * 3 + 0] * w;
        f1y += h1[n * 12 + v * 3 + 1] * w;
        f1z += h1[n * 12 + v * 3 + 2] * w;
    }
    float4 r;
    r.x = f0;
    r.y = f1x * 0.5f;                           // 1/sqrt(4)
    r.z = f1y * 0.5f;
    r.w = f1z * 0.5f;
    *reinterpret_cast<float4*>(out + (size_t)n * 128 + c * 4) = r;
}

extern "C" void kernel_launch(void* const* d_in, const int* in_sizes, int n_in,
                              void* d_out, int out_size, void* d_ws, size_t ws_size,
                              hipStream_t stream)
{
    const float* pos  = (const float*)d_in[0];
    const float* nf   = (const float*)d_in[1];
    const float* eain = (const float*)d_in[2];
    const int*   eidx = (const int*)  d_in[3];
    const float* encW = (const float*)d_in[4];
    const float* encb = (const float*)d_in[5];
    const float* neW1 = (const float*)d_in[6];
    const float* neb1 = (const float*)d_in[7];
    const float* neW2 = (const float*)d_in[8];
    const float* neb2 = (const float*)d_in[9];
    const float* eeW1 = (const float*)d_in[10];
    const float* eeb1 = (const float*)d_in[11];
    const float* eeW2 = (const float*)d_in[12];
    const float* eeb2 = (const float*)d_in[13];
    const float* reW1 = (const float*)d_in[14];
    const float* reb1 = (const float*)d_in[15];
    const float* reW2 = (const float*)d_in[16];
    const float* reb2 = (const float*)d_in[17];
    const float* fc1W = (const float*)d_in[18];
    const float* fc1b = (const float*)d_in[19];
    const float* fc2W = (const float*)d_in[20];
    const float* fc2b = (const float*)d_in[21];
    const float* lin0 = (const float*)d_in[22];
    const float* lin1 = (const float*)d_in[23];

    int N = in_sizes[0] / 3;
    int E = in_sizes[3] / 2;
    const int* srcI = eidx;
    const int* dstI = eidx + E;

    float* ws = (float*)d_ws;
    size_t o = 0;
    float* h0     = ws + o; o += (size_t)N * 16;
    float* h1     = ws + o; o += (size_t)N * 12;
    float* eat    = ws + o; o += (size_t)E * 16;
    float* y1s    = ws + o; o += (size_t)E * 3;
    float* oo0    = ws + o; o += (size_t)E * 16;
    float* oo1    = ws + o; o += (size_t)E * 12;
    float* invcnt = ws + o; o += (size_t)N;
    int* cntI   = (int*)(ws + o); o += (size_t)N;
    int* startA = (int*)(ws + o); o += (size_t)N;
    int* cursor = (int*)(ws + o); o += (size_t)N;
    int* perm   = (int*)(ws + o); o += (size_t)E;
    int* srcS   = (int*)(ws + o); o += (size_t)E;
    int* dstS   = (int*)(ws + o); o += (size_t)E;
    unsigned short* w2p = (unsigned short*)(ws + o); o += 2 * 26 * 2 * 64 * 8 / 2;

    hipMemsetAsync(h1,   0, sizeof(float) * (size_t)N * 12, stream);
    hipMemsetAsync(cntI, 0, sizeof(int) * (size_t)N, stream);

    pack_w2_kernel<<<26, 256, 0, stream>>>(fc2W, w2p);
    node_embed_kernel<<<(N + 255) / 256, 256, 0, stream>>>(
        nf, encW, encb, neW1, neb1, neW2, neb2, h0, N);

    hist_kernel<<<(E + 255) / 256, 256, 0, stream>>>(srcI, cntI, E);
    scan_kernel<<<1, 1024, 0, stream>>>(cntI, startA, cursor, invcnt, N);
    perm_kernel<<<(E + 255) / 256, 256, 0, stream>>>(srcI, cursor, perm, E);

    edge_pre_kernel<<<(E + 255) / 256, 256, 0, stream>>>(
        pos, eain, srcI, dstI, perm, eeW1, eeb1, eeW2, eeb2,
        reW1, reb1, reW2, reb2, eat, y1s, srcS, dstS, E);

    for (int i = 0; i < 2; ++i) {
        const float* fw1 = fc1W + (size_t)i * 48 * 64;
        const float* fb1 = fc1b + (size_t)i * 64;
        const float* fb2 = fc2b + (size_t)i * 416;
        const unsigned short* w2pi = w2p + (size_t)i * 26 * 2 * 64 * 8;
        if (i == 0) {
            fused_tp_kernel<false><<<E / 256, 256, 0, stream>>>(
                h0, h1, eat, y1s, srcS, dstS, fw1, fb1, w2pi, fb2, oo0, oo1, E);
        } else {
            fused_tp_kernel<true><<<E / 256, 256, 0, stream>>>(
                h0, h1, eat, y1s, srcS, dstS, fw1, fb1, w2pi, fb2, oo0, oo1, E);
        }
        dim3 blk(32, 8);
        node_update_kernel<<<(N + 7) / 8, blk, 0, stream>>>(
            h0, h1, oo0, oo1, startA, cntI, invcnt, N);
    }

    final_kernel<<<((size_t)N * 32 + 255) / 256, 256, 0, stream>>>(
        h0, h1, lin0, lin1, (float*)d_out, N);
}